// Round 1
// baseline (356.364 us; speedup 1.0000x reference)
//
#include <hip/hip_runtime.h>

typedef __bf16 bf16x8 __attribute__((ext_vector_type(8)));
typedef float f32x4 __attribute__((ext_vector_type(4)));
typedef unsigned short ushort8 __attribute__((ext_vector_type(8)));

__device__ __forceinline__ unsigned short f2bf(float f) {
  __bf16 b = (__bf16)f;
  return __builtin_bit_cast(unsigned short, b);
}

// ---------------- W transpose + f32->bf16 convert: Wt[n][k] = W[k][n] ----------------
__global__ __launch_bounds__(256) void wtrans_kernel(const float* __restrict__ W,
                                                     __bf16* __restrict__ Wt,
                                                     int K, int N) {
  __shared__ float tile[32][33];
  int tx = threadIdx.x, ty = threadIdx.y;  // block (32,8)
  int n0 = blockIdx.x * 32, k0 = blockIdx.y * 32;
#pragma unroll
  for (int i = 0; i < 32; i += 8)
    tile[ty + i][tx] = W[(size_t)(k0 + ty + i) * N + n0 + tx];
  __syncthreads();
#pragma unroll
  for (int i = 0; i < 32; i += 8)
    Wt[(size_t)(n0 + ty + i) * K + k0 + tx] = (__bf16)tile[tx][ty + i];
}

// ---------------- GEMM: C[M,N] = A[M,K] @ Bt[N,K]^T + bias ----------------
// 128x128 tile, BK=32, 4 waves (2x2), each wave 4x4 accs of 16x16x32 bf16 MFMA.
template <int A_F32, int OUT_F32>
__global__ __launch_bounds__(256) void gemm_bt_kernel(const void* __restrict__ Ap,
                                                      const __bf16* __restrict__ Bt,
                                                      const float* __restrict__ bias,
                                                      void* __restrict__ Cp,
                                                      int M, int N, int K) {
  __shared__ __align__(16) unsigned short As[128][40];  // pad 40: 2-way max on b128 reads
  __shared__ __align__(16) unsigned short Bs[128][40];
  const int tid = threadIdx.x;
  const int lane = tid & 63;
  const int wid = tid >> 6;
  const int lr = lane & 15, lg = lane >> 4;
  const int m0 = blockIdx.y * 128, n0 = blockIdx.x * 128;
  const int wm = (wid >> 1) * 64, wn = (wid & 1) * 64;
  f32x4 acc[4][4] = {};
  for (int k0 = 0; k0 < K; k0 += 32) {
#pragma unroll
    for (int p = 0; p < 2; ++p) {
      int idx = p * 256 + tid;
      int r = idx >> 2, c8 = (idx & 3) * 8;
      if (A_F32) {
        const float* A = (const float*)Ap;
        const float4* s4 = (const float4*)(A + (size_t)(m0 + r) * K + k0 + c8);
        float4 f0 = s4[0], f1 = s4[1];
        ushort8 u = {f2bf(f0.x), f2bf(f0.y), f2bf(f0.z), f2bf(f0.w),
                     f2bf(f1.x), f2bf(f1.y), f2bf(f1.z), f2bf(f1.w)};
        *(ushort8*)&As[r][c8] = u;
      } else {
        const __bf16* A = (const __bf16*)Ap;
        *(ushort8*)&As[r][c8] = *(const ushort8*)(A + (size_t)(m0 + r) * K + k0 + c8);
      }
      *(ushort8*)&Bs[r][c8] = *(const ushort8*)(Bt + (size_t)(n0 + r) * K + k0 + c8);
    }
    __syncthreads();
    bf16x8 af[4], bfr[4];
#pragma unroll
    for (int i = 0; i < 4; ++i) af[i] = *(const bf16x8*)&As[wm + i * 16 + lr][lg * 8];
#pragma unroll
    for (int i = 0; i < 4; ++i) bfr[i] = *(const bf16x8*)&Bs[wn + i * 16 + lr][lg * 8];
#pragma unroll
    for (int i = 0; i < 4; ++i)
#pragma unroll
      for (int jn = 0; jn < 4; ++jn)
        acc[i][jn] = __builtin_amdgcn_mfma_f32_16x16x32_bf16(af[i], bfr[jn], acc[i][jn], 0, 0, 0);
    __syncthreads();
  }
  // epilogue: C/D layout col=lane&15, row=(lane>>4)*4+reg
#pragma unroll
  for (int i = 0; i < 4; ++i)
#pragma unroll
    for (int jn = 0; jn < 4; ++jn)
#pragma unroll
      for (int jj = 0; jj < 4; ++jj) {
        int row = m0 + wm + i * 16 + lg * 4 + jj;
        int col = n0 + wn + jn * 16 + lr;
        float v = acc[i][jn][jj] + bias[col];
        if (OUT_F32)
          ((float*)Cp)[(size_t)row * N + col] = v;
        else
          ((unsigned short*)Cp)[(size_t)row * N + col] = f2bf(v);
      }
}

// ---------------- qkv -> Q,K [B,H,T,D] ----------------
__global__ __launch_bounds__(256) void reshape_qk_kernel(const __bf16* __restrict__ qkv,
                                                         __bf16* __restrict__ Q,
                                                         __bf16* __restrict__ Ko) {
  int tid = blockIdx.x * 256 + threadIdx.x;  // 1,048,576 threads
  int d8 = tid & 7;
  int t = (tid >> 3) & 2047;
  int h = (tid >> 14) & 15;
  int b = tid >> 18;
  size_t src = (size_t)(b * 2048 + t) * 3072 + h * 64 + d8 * 8;
  size_t dst = (size_t)((b * 16 + h) * 2048 + t) * 64 + d8 * 8;
  *(ushort8*)((unsigned short*)Q + dst) = *(const ushort8*)((const unsigned short*)qkv + src);
  *(ushort8*)((unsigned short*)Ko + dst) =
      *(const ushort8*)((const unsigned short*)qkv + src + 1024);
}

// ---------------- qkv(v part) -> Vt [B,H,D,T] (tiled transpose) ----------------
__global__ __launch_bounds__(256) void vtrans_kernel(const __bf16* __restrict__ qkv,
                                                     __bf16* __restrict__ Vt) {
  __shared__ __align__(16) unsigned short tile[64][72];
  int bh = blockIdx.y, b = bh >> 4, h = bh & 15;
  int t0 = blockIdx.x * 64;
  int tid = threadIdx.x;
#pragma unroll
  for (int p = 0; p < 2; ++p) {
    int idx = p * 256 + tid;
    int r = idx >> 3, c8 = (idx & 7) * 8;  // r = t row, c8 = d col
    *(ushort8*)&tile[r][c8] = *(const ushort8*)((const unsigned short*)qkv +
                                                (size_t)(b * 2048 + t0 + r) * 3072 + 2048 +
                                                h * 64 + c8);
  }
  __syncthreads();
#pragma unroll
  for (int p = 0; p < 2; ++p) {
    int idx = p * 256 + tid;
    int d = idx >> 3, c8 = (idx & 7) * 8;  // d = out row, c8 = t col
    ushort8 u;
#pragma unroll
    for (int i = 0; i < 8; ++i) u[i] = tile[c8 + i][d];
    *(ushort8*)((unsigned short*)Vt + (size_t)(bh * 64 + d) * 2048 + t0 + c8) = u;
  }
}

// ---------------- flash attention (causal), QBLK=64 (4 waves x 16 rows), KVBLK=64 ----------------
__global__ __launch_bounds__(256) void attn_kernel(const __bf16* __restrict__ Q,
                                                   const __bf16* __restrict__ Kg,
                                                   const __bf16* __restrict__ Vt,
                                                   __bf16* __restrict__ yb) {
  __shared__ __align__(16) unsigned short Ks[64][72];
  __shared__ __align__(16) unsigned short Vs[64][72];  // Vt tile: rows=d, cols=k
  __shared__ __align__(16) unsigned short Ps[64][72];  // per-wave 16-row slices
  const int bh = blockIdx.y, b = bh >> 4, h = bh & 15;
  const int qb = blockIdx.x;
  const int tid = threadIdx.x, wid = tid >> 6, lane = tid & 63;
  const int lr = lane & 15, lg = lane >> 4;
  const unsigned short* Qh = (const unsigned short*)Q + (size_t)bh * 2048 * 64;
  const unsigned short* Kh = (const unsigned short*)Kg + (size_t)bh * 2048 * 64;
  const unsigned short* Vh = (const unsigned short*)Vt + (size_t)bh * 64 * 2048;
  const int q0w = qb * 64 + wid * 16;
  bf16x8 qf[2];
#pragma unroll
  for (int dc = 0; dc < 2; ++dc)
    qf[dc] = *(const bf16x8*)(Qh + (size_t)(q0w + lr) * 64 + dc * 32 + lg * 8);
  f32x4 yacc[4] = {};
  float m_r[4] = {-1e30f, -1e30f, -1e30f, -1e30f};
  float l_r[4] = {0.f, 0.f, 0.f, 0.f};
  for (int j = 0; j <= qb; ++j) {
#pragma unroll
    for (int p = 0; p < 2; ++p) {
      int idx = p * 256 + tid;
      int r = idx >> 3, c8 = (idx & 7) * 8;
      *(ushort8*)&Ks[r][c8] = *(const ushort8*)(Kh + (size_t)(j * 64 + r) * 64 + c8);
      *(ushort8*)&Vs[r][c8] = *(const ushort8*)(Vh + (size_t)r * 2048 + j * 64 + c8);
    }
    __syncthreads();
    // S = Q K^T  (4 col-tiles of 16, K-dim = d = 64 -> 2 mfma each)
    f32x4 sa[4] = {};
#pragma unroll
    for (int ct = 0; ct < 4; ++ct)
#pragma unroll
      for (int dc = 0; dc < 2; ++dc) {
        bf16x8 kf = *(const bf16x8*)&Ks[ct * 16 + lr][dc * 32 + lg * 8];
        sa[ct] = __builtin_amdgcn_mfma_f32_16x16x32_bf16(qf[dc], kf, sa[ct], 0, 0, 0);
      }
    // online softmax; rows held per reg jj across 16-lane groups
    float alpha[4];
#pragma unroll
    for (int jj = 0; jj < 4; ++jj) {
      float rm = -1e30f;
#pragma unroll
      for (int ct = 0; ct < 4; ++ct) {
        float s = sa[ct][jj] * 0.125f;
        if (j == qb && (ct * 16 + lr) > (wid * 16 + lg * 4 + jj)) s = -1e30f;
        sa[ct][jj] = s;
        rm = fmaxf(rm, s);
      }
      rm = fmaxf(rm, __shfl_xor(rm, 1));
      rm = fmaxf(rm, __shfl_xor(rm, 2));
      rm = fmaxf(rm, __shfl_xor(rm, 4));
      rm = fmaxf(rm, __shfl_xor(rm, 8));
      float mnew = fmaxf(m_r[jj], rm);
      alpha[jj] = __expf(m_r[jj] - mnew);
      float rs = 0.f;
#pragma unroll
      for (int ct = 0; ct < 4; ++ct) {
        float pv = __expf(sa[ct][jj] - mnew);
        Ps[wid * 16 + lg * 4 + jj][ct * 16 + lr] = f2bf(pv);
        rs += pv;
      }
      rs += __shfl_xor(rs, 1);
      rs += __shfl_xor(rs, 2);
      rs += __shfl_xor(rs, 4);
      rs += __shfl_xor(rs, 8);
      l_r[jj] = l_r[jj] * alpha[jj] + rs;
      m_r[jj] = mnew;
    }
    // Y += P V  (P re-read from wave-private LDS slice in A-fragment layout)
#pragma unroll
    for (int dt = 0; dt < 4; ++dt) {
      f32x4 y = yacc[dt];
#pragma unroll
      for (int jj = 0; jj < 4; ++jj) y[jj] *= alpha[jj];
#pragma unroll
      for (int kc = 0; kc < 2; ++kc) {
        bf16x8 pf = *(const bf16x8*)&Ps[wid * 16 + lr][kc * 32 + lg * 8];
        bf16x8 vf = *(const bf16x8*)&Vs[dt * 16 + lr][kc * 32 + lg * 8];
        y = __builtin_amdgcn_mfma_f32_16x16x32_bf16(pf, vf, y, 0, 0, 0);
      }
      yacc[dt] = y;
    }
    __syncthreads();
  }
  // epilogue: y / l -> yb [B,T,C] bf16
#pragma unroll
  for (int dt = 0; dt < 4; ++dt)
#pragma unroll
    for (int jj = 0; jj < 4; ++jj) {
      int q = q0w + lg * 4 + jj;
      float v = yacc[dt][jj] / l_r[jj];
      ((unsigned short*)yb)[(size_t)(b * 2048 + q) * 1024 + h * 64 + dt * 16 + lr] = f2bf(v);
    }
}

extern "C" void kernel_launch(void* const* d_in, const int* in_sizes, int n_in,
                              void* d_out, int out_size, void* d_ws, size_t ws_size,
                              hipStream_t stream) {
  const float* x = (const float*)d_in[0];
  const float* W_attn = (const float*)d_in[1];
  const float* b_attn = (const float*)d_in[2];
  const float* W_proj = (const float*)d_in[3];
  const float* b_proj = (const float*)d_in[4];
  float* out = (float*)d_out;
  char* ws = (char*)d_ws;

  size_t off = 0;
  __bf16* WtA = (__bf16*)(ws + off); off += (size_t)3072 * 1024 * 2;
  __bf16* WtP = (__bf16*)(ws + off); off += (size_t)1024 * 1024 * 2;
  __bf16* qkv = (__bf16*)(ws + off); off += (size_t)8192 * 3072 * 2;
  __bf16* Qb  = (__bf16*)(ws + off); off += (size_t)64 * 2048 * 64 * 2;
  __bf16* Kb  = (__bf16*)(ws + off); off += (size_t)64 * 2048 * 64 * 2;
  __bf16* Vtb = (__bf16*)(ws + off); off += (size_t)64 * 2048 * 64 * 2;
  __bf16* yb  = (__bf16*)(ws + off); off += (size_t)8192 * 1024 * 2;
  (void)ws_size; (void)in_sizes; (void)n_in; (void)out_size;

  // W_attn [1024,3072] -> WtA [3072,1024]; W_proj [1024,1024] -> WtP
  wtrans_kernel<<<dim3(3072 / 32, 1024 / 32), dim3(32, 8), 0, stream>>>(W_attn, WtA, 1024, 3072);
  wtrans_kernel<<<dim3(1024 / 32, 1024 / 32), dim3(32, 8), 0, stream>>>(W_proj, WtP, 1024, 1024);
  // qkv = x @ W_attn + b_attn  (f32 A staged->bf16, bf16 out)
  gemm_bt_kernel<1, 0><<<dim3(24, 64), 256, 0, stream>>>(x, WtA, b_attn, qkv, 8192, 3072, 1024);
  // reshape
  reshape_qk_kernel<<<4096, 256, 0, stream>>>(qkv, Qb, Kb);
  vtrans_kernel<<<dim3(32, 64), 256, 0, stream>>>(qkv, Vtb);
  // attention
  attn_kernel<<<dim3(32, 64), 256, 0, stream>>>(Qb, Kb, Vtb, yb);
  // out = y @ W_proj + b_proj  (bf16 A, f32 out)
  gemm_bt_kernel<0, 1><<<dim3(8, 64), 256, 0, stream>>>(yb, WtP, b_proj, out, 8192, 1024, 1024);
}

// Round 2
// 218.974 us; speedup vs baseline: 1.6274x; 1.6274x over previous
//
#include <hip/hip_runtime.h>

typedef __bf16 bf16x8 __attribute__((ext_vector_type(8)));
typedef float f32x4 __attribute__((ext_vector_type(4)));
typedef float f32x16 __attribute__((ext_vector_type(16)));
typedef unsigned short ushort8 __attribute__((ext_vector_type(8)));
typedef unsigned int uint4v __attribute__((ext_vector_type(4)));

__device__ __forceinline__ unsigned short f2bf(float f) {
  __bf16 b = (__bf16)f;
  return __builtin_bit_cast(unsigned short, b);
}

// ---------------- W transpose + f32->bf16 convert: Wt[n][k] = W[k][n] ----------------
__global__ __launch_bounds__(256) void wtrans_kernel(const float* __restrict__ W,
                                                     __bf16* __restrict__ Wt,
                                                     int K, int N) {
  __shared__ float tile[32][33];
  int tx = threadIdx.x, ty = threadIdx.y;  // block (32,8)
  int n0 = blockIdx.x * 32, k0 = blockIdx.y * 32;
#pragma unroll
  for (int i = 0; i < 32; i += 8)
    tile[ty + i][tx] = W[(size_t)(k0 + ty + i) * N + n0 + tx];
  __syncthreads();
#pragma unroll
  for (int i = 0; i < 32; i += 8)
    Wt[(size_t)(n0 + ty + i) * K + k0 + tx] = (__bf16)tile[tx][ty + i];
}

// ---------------- GEMM: C[M,N] = A[M,K] @ Bt[N,K]^T + bias ----------------
template <int A_F32, int OUT_F32>
__global__ __launch_bounds__(256) void gemm_bt_kernel(const void* __restrict__ Ap,
                                                      const __bf16* __restrict__ Bt,
                                                      const float* __restrict__ bias,
                                                      void* __restrict__ Cp,
                                                      int M, int N, int K) {
  __shared__ __align__(16) unsigned short As[128][40];
  __shared__ __align__(16) unsigned short Bs[128][40];
  const int tid = threadIdx.x;
  const int lane = tid & 63;
  const int wid = tid >> 6;
  const int lr = lane & 15, lg = lane >> 4;
  const int m0 = blockIdx.y * 128, n0 = blockIdx.x * 128;
  const int wm = (wid >> 1) * 64, wn = (wid & 1) * 64;
  f32x4 acc[4][4] = {};
  for (int k0 = 0; k0 < K; k0 += 32) {
#pragma unroll
    for (int p = 0; p < 2; ++p) {
      int idx = p * 256 + tid;
      int r = idx >> 2, c8 = (idx & 3) * 8;
      if (A_F32) {
        const float* A = (const float*)Ap;
        const float4* s4 = (const float4*)(A + (size_t)(m0 + r) * K + k0 + c8);
        float4 f0 = s4[0], f1 = s4[1];
        ushort8 u = {f2bf(f0.x), f2bf(f0.y), f2bf(f0.z), f2bf(f0.w),
                     f2bf(f1.x), f2bf(f1.y), f2bf(f1.z), f2bf(f1.w)};
        *(ushort8*)&As[r][c8] = u;
      } else {
        const __bf16* A = (const __bf16*)Ap;
        *(ushort8*)&As[r][c8] = *(const ushort8*)(A + (size_t)(m0 + r) * K + k0 + c8);
      }
      *(ushort8*)&Bs[r][c8] = *(const ushort8*)(Bt + (size_t)(n0 + r) * K + k0 + c8);
    }
    __syncthreads();
    bf16x8 af[4], bfr[4];
#pragma unroll
    for (int i = 0; i < 4; ++i) af[i] = *(const bf16x8*)&As[wm + i * 16 + lr][lg * 8];
#pragma unroll
    for (int i = 0; i < 4; ++i) bfr[i] = *(const bf16x8*)&Bs[wn + i * 16 + lr][lg * 8];
#pragma unroll
    for (int i = 0; i < 4; ++i)
#pragma unroll
      for (int jn = 0; jn < 4; ++jn)
        acc[i][jn] = __builtin_amdgcn_mfma_f32_16x16x32_bf16(af[i], bfr[jn], acc[i][jn], 0, 0, 0);
    __syncthreads();
  }
#pragma unroll
  for (int i = 0; i < 4; ++i)
#pragma unroll
    for (int jn = 0; jn < 4; ++jn)
#pragma unroll
      for (int jj = 0; jj < 4; ++jj) {
        int row = m0 + wm + i * 16 + lg * 4 + jj;
        int col = n0 + wn + jn * 16 + lr;
        float v = acc[i][jn][jj] + bias[col];
        if (OUT_F32)
          ((float*)Cp)[(size_t)row * N + col] = v;
        else
          ((unsigned short*)Cp)[(size_t)row * N + col] = f2bf(v);
      }
}

// ---------------- qkv -> Q,K [B,H,T,D] ----------------
__global__ __launch_bounds__(256) void reshape_qk_kernel(const __bf16* __restrict__ qkv,
                                                         __bf16* __restrict__ Q,
                                                         __bf16* __restrict__ Ko) {
  int tid = blockIdx.x * 256 + threadIdx.x;
  int d8 = tid & 7;
  int t = (tid >> 3) & 2047;
  int h = (tid >> 14) & 15;
  int b = tid >> 18;
  size_t src = (size_t)(b * 2048 + t) * 3072 + h * 64 + d8 * 8;
  size_t dst = (size_t)((b * 16 + h) * 2048 + t) * 64 + d8 * 8;
  *(ushort8*)((unsigned short*)Q + dst) = *(const ushort8*)((const unsigned short*)qkv + src);
  *(ushort8*)((unsigned short*)Ko + dst) =
      *(const ushort8*)((const unsigned short*)qkv + src + 1024);
}

// ---------------- qkv(v part) -> Vt [B,H,D,T] (tiled transpose) ----------------
__global__ __launch_bounds__(256) void vtrans_kernel(const __bf16* __restrict__ qkv,
                                                     __bf16* __restrict__ Vt) {
  __shared__ __align__(16) unsigned short tile[64][72];
  int bh = blockIdx.y, b = bh >> 4, h = bh & 15;
  int t0 = blockIdx.x * 64;
  int tid = threadIdx.x;
#pragma unroll
  for (int p = 0; p < 2; ++p) {
    int idx = p * 256 + tid;
    int r = idx >> 3, c8 = (idx & 7) * 8;
    *(ushort8*)&tile[r][c8] = *(const ushort8*)((const unsigned short*)qkv +
                                                (size_t)(b * 2048 + t0 + r) * 3072 + 2048 +
                                                h * 64 + c8);
  }
  __syncthreads();
#pragma unroll
  for (int p = 0; p < 2; ++p) {
    int idx = p * 256 + tid;
    int d = idx >> 3, c8 = (idx & 7) * 8;
    ushort8 u;
#pragma unroll
    for (int i = 0; i < 8; ++i) u[i] = tile[c8 + i][d];
    *(ushort8*)((unsigned short*)Vt + (size_t)(bh * 64 + d) * 2048 + t0 + c8) = u;
  }
}

// ---------------- flash attention (causal), swapped-QK^T 32x32 structure ----------------
// QBLK=128 (4 waves x 32 q-rows), KVBLK=64, double-buffered K/V LDS, 1 barrier/iter.
// S^T = mfma(K_frag, Q_frag): lane owns q=lane&31's k-slice -> in-reg softmax,
// cvt_pk + permlane32_swap repack P into PV A-fragments (no LDS round trip).
__global__ __launch_bounds__(256) void attn_kernel(const __bf16* __restrict__ Q,
                                                   const __bf16* __restrict__ Kg,
                                                   const __bf16* __restrict__ Vt,
                                                   __bf16* __restrict__ yb) {
  __shared__ __align__(16) unsigned short Ks[2][64][72];
  __shared__ __align__(16) unsigned short Vs[2][64][72];
  const int bx = blockIdx.x;
  const int qb = 15 - (bx >> 6);  // heavy blocks first
  const int bh = bx & 63;
  const int b = bh >> 4, h = bh & 15;
  const int tid = threadIdx.x, wid = tid >> 6, lane = tid & 63;
  const int lq = lane & 31, hi = lane >> 5;
  const unsigned short* Qh = (const unsigned short*)Q + (size_t)bh * 2048 * 64;
  const unsigned short* Kh = (const unsigned short*)Kg + (size_t)bh * 2048 * 64;
  const unsigned short* Vh = (const unsigned short*)Vt + (size_t)bh * 64 * 2048;
  const int q0w = qb * 128 + wid * 32;
  const int jmax_w = 2 * qb + (wid >> 1);
  const int qrel = (wid & 1) * 32 + lq;
  const int J = 2 * qb + 2;

  // Q B-fragments: lane holds Q[q=lq][d = dc*16 + hi*8 + i]
  bf16x8 qf[4];
#pragma unroll
  for (int dc = 0; dc < 4; ++dc)
    qf[dc] = *(const bf16x8*)(Qh + (size_t)(q0w + lq) * 64 + dc * 16 + hi * 8);

  f32x16 yacc[2] = {};
  float m_r = -1e30f, l_r = 0.f;
  const float sc = 0.125f * 1.44269504f;  // 1/sqrt(64) * log2(e)

  // stage tile 0 into buffer 0
  {
#pragma unroll
    for (int p = 0; p < 2; ++p) {
      int idx = p * 256 + tid;
      int r = idx >> 3, c8 = (idx & 7) * 8;
      *(ushort8*)&Ks[0][r][c8] = *(const ushort8*)(Kh + (size_t)r * 64 + c8);
      *(ushort8*)&Vs[0][r][c8] = *(const ushort8*)(Vh + (size_t)r * 2048 + c8);
    }
  }

  for (int j = 0; j < J; ++j) {
    __syncthreads();  // staged tile j ready; prior reads of buf (j&1)^1 done
    if (j + 1 < J) {
      int bi = (j + 1) & 1;
#pragma unroll
      for (int p = 0; p < 2; ++p) {
        int idx = p * 256 + tid;
        int r = idx >> 3, c8 = (idx & 7) * 8;
        *(ushort8*)&Ks[bi][r][c8] =
            *(const ushort8*)(Kh + (size_t)((j + 1) * 64 + r) * 64 + c8);
        *(ushort8*)&Vs[bi][r][c8] =
            *(const ushort8*)(Vh + (size_t)r * 2048 + (j + 1) * 64 + c8);
      }
    }
    if (j <= jmax_w) {
      const int cb = j & 1;
      // --- S^T = K @ Q^T : sa[kt32][reg] = St[k_local][q=lq]
      f32x16 sa[2];
#pragma unroll
      for (int kt32 = 0; kt32 < 2; ++kt32) {
        f32x16 s = {};
#pragma unroll
        for (int dc = 0; dc < 4; ++dc) {
          bf16x8 kf = *(const bf16x8*)&Ks[cb][kt32 * 32 + lq][dc * 16 + hi * 8];
          s = __builtin_amdgcn_mfma_f32_32x32x16_bf16(kf, qf[dc], s, 0, 0, 0);
        }
        sa[kt32] = s;
      }
      // --- scale + causal mask + row max (k spread over regs + hi pair)
      float pmax = -1e30f;
#pragma unroll
      for (int kt32 = 0; kt32 < 2; ++kt32)
#pragma unroll
        for (int reg = 0; reg < 16; ++reg) {
          float v = sa[kt32][reg] * sc;
          int kl = kt32 * 32 + (reg & 3) + 8 * (reg >> 2) + 4 * hi;
          if (j == jmax_w && kl > qrel) v = -1e30f;
          sa[kt32][reg] = v;
          pmax = fmaxf(pmax, v);
        }
      pmax = fmaxf(pmax, __shfl_xor(pmax, 32));
      const bool need = __any(pmax > m_r + 8.f) != 0;
      const float mnew = need ? fmaxf(m_r, pmax) : m_r;
      const float alpha = exp2f(m_r - mnew);
      // --- exp + row sum + pack to bf16 pairs
      unsigned int u[2][8];
      float rs = 0.f;
#pragma unroll
      for (int kt32 = 0; kt32 < 2; ++kt32)
#pragma unroll
        for (int r = 0; r < 8; ++r) {
          float p0 = exp2f(sa[kt32][2 * r] - mnew);
          float p1 = exp2f(sa[kt32][2 * r + 1] - mnew);
          rs += p0 + p1;
          unsigned int up;
          asm("v_cvt_pk_bf16_f32 %0, %1, %2" : "=v"(up) : "v"(p0), "v"(p1));
          u[kt32][r] = up;
        }
      rs += __shfl_xor(rs, 32);
      l_r = l_r * alpha + rs;
      m_r = mnew;
      if (need) {  // O-rescale (rare after first tile): alpha to C-layout rows
#pragma unroll
        for (int reg = 0; reg < 16; ++reg) {
          int row = (reg & 3) + 8 * (reg >> 2) + 4 * hi;
          float ac = __shfl(alpha, row);
          yacc[0][reg] *= ac;
          yacc[1][reg] *= ac;
        }
      }
      // --- PV: repack P via permlane32_swap, accumulate Y
#pragma unroll
      for (int kt = 0; kt < 4; ++kt) {
        const int kt32 = kt >> 1, off = 4 * (kt & 1);
        unsigned int a0 = u[kt32][off + 0], a2 = u[kt32][off + 2];
        unsigned int a1 = u[kt32][off + 1], a3 = u[kt32][off + 3];
        asm("v_permlane32_swap_b32 %0, %1" : "+v"(a0), "+v"(a2));
        asm("v_permlane32_swap_b32 %0, %1" : "+v"(a1), "+v"(a3));
        uint4v pav = {a0, a1, a2, a3};
        bf16x8 paf = __builtin_bit_cast(bf16x8, pav);
#pragma unroll
        for (int dt = 0; dt < 2; ++dt) {
          bf16x8 vf = *(const bf16x8*)&Vs[cb][dt * 32 + lq][kt * 16 + hi * 8];
          yacc[dt] = __builtin_amdgcn_mfma_f32_32x32x16_bf16(paf, vf, yacc[dt], 0, 0, 0);
        }
      }
    }
  }
  // --- epilogue: divide by l (C-layout rows via shuffle), store bf16 y
#pragma unroll
  for (int reg = 0; reg < 16; ++reg) {
    int row = (reg & 3) + 8 * (reg >> 2) + 4 * hi;
    float linv = 1.f / __shfl(l_r, row);
    int qg = q0w + row;
#pragma unroll
    for (int dt = 0; dt < 2; ++dt) {
      float v = yacc[dt][reg] * linv;
      ((unsigned short*)yb)[(size_t)(b * 2048 + qg) * 1024 + h * 64 + dt * 32 + lq] = f2bf(v);
    }
  }
}

extern "C" void kernel_launch(void* const* d_in, const int* in_sizes, int n_in,
                              void* d_out, int out_size, void* d_ws, size_t ws_size,
                              hipStream_t stream) {
  const float* x = (const float*)d_in[0];
  const float* W_attn = (const float*)d_in[1];
  const float* b_attn = (const float*)d_in[2];
  const float* W_proj = (const float*)d_in[3];
  const float* b_proj = (const float*)d_in[4];
  float* out = (float*)d_out;
  char* ws = (char*)d_ws;

  size_t off = 0;
  __bf16* WtA = (__bf16*)(ws + off); off += (size_t)3072 * 1024 * 2;
  __bf16* WtP = (__bf16*)(ws + off); off += (size_t)1024 * 1024 * 2;
  __bf16* qkv = (__bf16*)(ws + off); off += (size_t)8192 * 3072 * 2;
  __bf16* Qb  = (__bf16*)(ws + off); off += (size_t)64 * 2048 * 64 * 2;
  __bf16* Kb  = (__bf16*)(ws + off); off += (size_t)64 * 2048 * 64 * 2;
  __bf16* Vtb = (__bf16*)(ws + off); off += (size_t)64 * 2048 * 64 * 2;
  __bf16* yb  = (__bf16*)(ws + off); off += (size_t)8192 * 1024 * 2;
  (void)ws_size; (void)in_sizes; (void)n_in; (void)out_size;

  wtrans_kernel<<<dim3(3072 / 32, 1024 / 32), dim3(32, 8), 0, stream>>>(W_attn, WtA, 1024, 3072);
  wtrans_kernel<<<dim3(1024 / 32, 1024 / 32), dim3(32, 8), 0, stream>>>(W_proj, WtP, 1024, 1024);
  gemm_bt_kernel<1, 0><<<dim3(24, 64), 256, 0, stream>>>(x, WtA, b_attn, qkv, 8192, 3072, 1024);
  reshape_qk_kernel<<<4096, 256, 0, stream>>>(qkv, Qb, Kb);
  vtrans_kernel<<<dim3(32, 64), 256, 0, stream>>>(qkv, Vtb);
  attn_kernel<<<dim3(1024), 256, 0, stream>>>(Qb, Kb, Vtb, yb);
  gemm_bt_kernel<0, 1><<<dim3(8, 64), 256, 0, stream>>>(yb, WtP, b_proj, out, 8192, 1024, 1024);
}

// Round 3
// 209.088 us; speedup vs baseline: 1.7044x; 1.0473x over previous
//
#include <hip/hip_runtime.h>

typedef __bf16 bf16x8 __attribute__((ext_vector_type(8)));
typedef float f32x4 __attribute__((ext_vector_type(4)));
typedef float f32x16 __attribute__((ext_vector_type(16)));
typedef unsigned short ushort8 __attribute__((ext_vector_type(8)));
typedef unsigned int uint4v __attribute__((ext_vector_type(4)));

__device__ __forceinline__ unsigned short f2bf(float f) {
  __bf16 b = (__bf16)f;
  return __builtin_bit_cast(unsigned short, b);
}

// async global->LDS, 16B per lane; LDS dest must be wave-uniform base + lane*16
#define GLOAD_LDS16(g, l)                                              \
  __builtin_amdgcn_global_load_lds(                                    \
      (const __attribute__((address_space(1))) void*)(g),              \
      (__attribute__((address_space(3))) void*)(l), 16, 0, 0)

// ---------------- x f32 -> bf16 ----------------
__global__ __launch_bounds__(256) void f32_to_bf16_kernel(const float* __restrict__ in,
                                                          __bf16* __restrict__ out) {
  int i = blockIdx.x * 256 + threadIdx.x;  // one ushort8 per thread
  const float4* p = (const float4*)(in + (size_t)i * 8);
  float4 f0 = p[0], f1 = p[1];
  ushort8 u = {f2bf(f0.x), f2bf(f0.y), f2bf(f0.z), f2bf(f0.w),
               f2bf(f1.x), f2bf(f1.y), f2bf(f1.z), f2bf(f1.w)};
  *(ushort8*)((unsigned short*)out + (size_t)i * 8) = u;
}

// ---------------- W transpose + f32->bf16 convert: Wt[n][k] = W[k][n] ----------------
__global__ __launch_bounds__(256) void wtrans_kernel(const float* __restrict__ W,
                                                     __bf16* __restrict__ Wt,
                                                     int K, int N) {
  __shared__ float tile[32][33];
  int tx = threadIdx.x, ty = threadIdx.y;  // block (32,8)
  int n0 = blockIdx.x * 32, k0 = blockIdx.y * 32;
#pragma unroll
  for (int i = 0; i < 32; i += 8)
    tile[ty + i][tx] = W[(size_t)(k0 + ty + i) * N + n0 + tx];
  __syncthreads();
#pragma unroll
  for (int i = 0; i < 32; i += 8)
    Wt[(size_t)(n0 + ty + i) * K + k0 + tx] = (__bf16)tile[tx][ty + i];
}

// ---------------- GEMM: C[M,N] = A[M,K] @ Bt[N,K]^T + bias ----------------
// m97 structure: 128x128 tile, BK=32, linear LDS, global_load_lds staging, 2 barriers/K-step.
template <int OUT_F32>
__global__ __launch_bounds__(256) void gemm_bt_kernel(const __bf16* __restrict__ Ab,
                                                      const __bf16* __restrict__ Bt,
                                                      const float* __restrict__ bias,
                                                      void* __restrict__ Cp,
                                                      int M, int N, int K) {
  __shared__ __align__(16) unsigned short As[128 * 32];
  __shared__ __align__(16) unsigned short Bs[128 * 32];
  const int tid = threadIdx.x;
  const int lane = tid & 63;
  const int wid = tid >> 6;
  const int lr = lane & 15, lg = lane >> 4;
  // XCD-aware swizzle of linearized block id (grid % 8 == 0 for our launches)
  const int gx = gridDim.x;
  int nwg = gx * gridDim.y;
  int bid = blockIdx.y * gx + blockIdx.x;
  if ((nwg & 7) == 0) {
    int cpx = nwg >> 3;
    bid = (bid & 7) * cpx + (bid >> 3);
  }
  const int m0 = (bid / gx) * 128, n0 = (bid % gx) * 128;
  const int wm = (wid >> 1) * 64, wn = (wid & 1) * 64;
  // staging coords: 256 threads cover 64 rows x 32 cols (16B each) per issue
  const int sr = tid >> 2, sc = (tid & 3) * 8;
  const unsigned short* Ag = (const unsigned short*)Ab + (size_t)(m0 + sr) * K + sc;
  const unsigned short* Bg = (const unsigned short*)Bt + (size_t)(n0 + sr) * K + sc;
  f32x4 acc[4][4] = {};
  for (int k0 = 0; k0 < K; k0 += 32) {
    GLOAD_LDS16(Ag + k0, As + tid * 8);
    GLOAD_LDS16(Ag + (size_t)64 * K + k0, As + 2048 + tid * 8);
    GLOAD_LDS16(Bg + k0, Bs + tid * 8);
    GLOAD_LDS16(Bg + (size_t)64 * K + k0, Bs + 2048 + tid * 8);
    __syncthreads();  // drains vmcnt -> staged tile visible
    bf16x8 af[4], bfr[4];
#pragma unroll
    for (int i = 0; i < 4; ++i) af[i] = *(const bf16x8*)&As[(wm + i * 16 + lr) * 32 + lg * 8];
#pragma unroll
    for (int i = 0; i < 4; ++i) bfr[i] = *(const bf16x8*)&Bs[(wn + i * 16 + lr) * 32 + lg * 8];
#pragma unroll
    for (int i = 0; i < 4; ++i)
#pragma unroll
      for (int jn = 0; jn < 4; ++jn)
        acc[i][jn] = __builtin_amdgcn_mfma_f32_16x16x32_bf16(af[i], bfr[jn], acc[i][jn], 0, 0, 0);
    __syncthreads();  // all reads done before next-iter staging overwrites
  }
#pragma unroll
  for (int i = 0; i < 4; ++i)
#pragma unroll
    for (int jn = 0; jn < 4; ++jn)
#pragma unroll
      for (int jj = 0; jj < 4; ++jj) {
        int row = m0 + wm + i * 16 + lg * 4 + jj;
        int col = n0 + wn + jn * 16 + lr;
        float v = acc[i][jn][jj] + bias[col];
        if (OUT_F32)
          ((float*)Cp)[(size_t)row * N + col] = v;
        else
          ((unsigned short*)Cp)[(size_t)row * N + col] = f2bf(v);
      }
}

// ---------------- qkv -> Q,K [B,H,T,D] ----------------
__global__ __launch_bounds__(256) void reshape_qk_kernel(const __bf16* __restrict__ qkv,
                                                         __bf16* __restrict__ Q,
                                                         __bf16* __restrict__ Ko) {
  int tid = blockIdx.x * 256 + threadIdx.x;
  int d8 = tid & 7;
  int t = (tid >> 3) & 2047;
  int h = (tid >> 14) & 15;
  int b = tid >> 18;
  size_t src = (size_t)(b * 2048 + t) * 3072 + h * 64 + d8 * 8;
  size_t dst = (size_t)((b * 16 + h) * 2048 + t) * 64 + d8 * 8;
  *(ushort8*)((unsigned short*)Q + dst) = *(const ushort8*)((const unsigned short*)qkv + src);
  *(ushort8*)((unsigned short*)Ko + dst) =
      *(const ushort8*)((const unsigned short*)qkv + src + 1024);
}

// ---------------- qkv(v part) -> Vt [B,H,D,T] (tiled transpose) ----------------
__global__ __launch_bounds__(256) void vtrans_kernel(const __bf16* __restrict__ qkv,
                                                     __bf16* __restrict__ Vt) {
  __shared__ __align__(16) unsigned short tile[64][72];
  int bh = blockIdx.y, b = bh >> 4, h = bh & 15;
  int t0 = blockIdx.x * 64;
  int tid = threadIdx.x;
#pragma unroll
  for (int p = 0; p < 2; ++p) {
    int idx = p * 256 + tid;
    int r = idx >> 3, c8 = (idx & 7) * 8;
    *(ushort8*)&tile[r][c8] = *(const ushort8*)((const unsigned short*)qkv +
                                                (size_t)(b * 2048 + t0 + r) * 3072 + 2048 +
                                                h * 64 + c8);
  }
  __syncthreads();
#pragma unroll
  for (int p = 0; p < 2; ++p) {
    int idx = p * 256 + tid;
    int d = idx >> 3, c8 = (idx & 7) * 8;
    ushort8 u;
#pragma unroll
    for (int i = 0; i < 8; ++i) u[i] = tile[c8 + i][d];
    *(ushort8*)((unsigned short*)Vt + (size_t)(bh * 64 + d) * 2048 + t0 + c8) = u;
  }
}

// ---------------- flash attention (causal), swapped-QK^T 32x32 structure ----------------
__global__ __launch_bounds__(256) void attn_kernel(const __bf16* __restrict__ Q,
                                                   const __bf16* __restrict__ Kg,
                                                   const __bf16* __restrict__ Vt,
                                                   __bf16* __restrict__ yb) {
  __shared__ __align__(16) unsigned short Ks[2][64][72];
  __shared__ __align__(16) unsigned short Vs[2][64][72];
  const int bx = blockIdx.x;
  const int qb = 15 - (bx >> 6);  // heavy blocks first
  const int bh = bx & 63;
  const int b = bh >> 4, h = bh & 15;
  const int tid = threadIdx.x, wid = tid >> 6, lane = tid & 63;
  const int lq = lane & 31, hi = lane >> 5;
  const unsigned short* Qh = (const unsigned short*)Q + (size_t)bh * 2048 * 64;
  const unsigned short* Kh = (const unsigned short*)Kg + (size_t)bh * 2048 * 64;
  const unsigned short* Vh = (const unsigned short*)Vt + (size_t)bh * 64 * 2048;
  const int q0w = qb * 128 + wid * 32;
  const int jmax_w = 2 * qb + (wid >> 1);
  const int qrel = (wid & 1) * 32 + lq;
  const int J = 2 * qb + 2;

  bf16x8 qf[4];
#pragma unroll
  for (int dc = 0; dc < 4; ++dc)
    qf[dc] = *(const bf16x8*)(Qh + (size_t)(q0w + lq) * 64 + dc * 16 + hi * 8);

  f32x16 yacc[2] = {};
  float m_r = -1e30f, l_r = 0.f;
  const float sc = 0.125f * 1.44269504f;

  {
#pragma unroll
    for (int p = 0; p < 2; ++p) {
      int idx = p * 256 + tid;
      int r = idx >> 3, c8 = (idx & 7) * 8;
      *(ushort8*)&Ks[0][r][c8] = *(const ushort8*)(Kh + (size_t)r * 64 + c8);
      *(ushort8*)&Vs[0][r][c8] = *(const ushort8*)(Vh + (size_t)r * 2048 + c8);
    }
  }

  for (int j = 0; j < J; ++j) {
    __syncthreads();
    if (j + 1 < J) {
      int bi = (j + 1) & 1;
#pragma unroll
      for (int p = 0; p < 2; ++p) {
        int idx = p * 256 + tid;
        int r = idx >> 3, c8 = (idx & 7) * 8;
        *(ushort8*)&Ks[bi][r][c8] =
            *(const ushort8*)(Kh + (size_t)((j + 1) * 64 + r) * 64 + c8);
        *(ushort8*)&Vs[bi][r][c8] =
            *(const ushort8*)(Vh + (size_t)r * 2048 + (j + 1) * 64 + c8);
      }
    }
    if (j <= jmax_w) {
      const int cb = j & 1;
      f32x16 sa[2];
#pragma unroll
      for (int kt32 = 0; kt32 < 2; ++kt32) {
        f32x16 s = {};
#pragma unroll
        for (int dc = 0; dc < 4; ++dc) {
          bf16x8 kf = *(const bf16x8*)&Ks[cb][kt32 * 32 + lq][dc * 16 + hi * 8];
          s = __builtin_amdgcn_mfma_f32_32x32x16_bf16(kf, qf[dc], s, 0, 0, 0);
        }
        sa[kt32] = s;
      }
      float pmax = -1e30f;
#pragma unroll
      for (int kt32 = 0; kt32 < 2; ++kt32)
#pragma unroll
        for (int reg = 0; reg < 16; ++reg) {
          float v = sa[kt32][reg] * sc;
          int kl = kt32 * 32 + (reg & 3) + 8 * (reg >> 2) + 4 * hi;
          if (j == jmax_w && kl > qrel) v = -1e30f;
          sa[kt32][reg] = v;
          pmax = fmaxf(pmax, v);
        }
      pmax = fmaxf(pmax, __shfl_xor(pmax, 32));
      const bool need = __any(pmax > m_r + 8.f) != 0;
      const float mnew = need ? fmaxf(m_r, pmax) : m_r;
      const float alpha = exp2f(m_r - mnew);
      unsigned int u[2][8];
      float rs = 0.f;
#pragma unroll
      for (int kt32 = 0; kt32 < 2; ++kt32)
#pragma unroll
        for (int r = 0; r < 8; ++r) {
          float p0 = exp2f(sa[kt32][2 * r] - mnew);
          float p1 = exp2f(sa[kt32][2 * r + 1] - mnew);
          rs += p0 + p1;
          unsigned int up;
          asm("v_cvt_pk_bf16_f32 %0, %1, %2" : "=v"(up) : "v"(p0), "v"(p1));
          u[kt32][r] = up;
        }
      rs += __shfl_xor(rs, 32);
      l_r = l_r * alpha + rs;
      m_r = mnew;
      if (need) {
#pragma unroll
        for (int reg = 0; reg < 16; ++reg) {
          int row = (reg & 3) + 8 * (reg >> 2) + 4 * hi;
          float ac = __shfl(alpha, row);
          yacc[0][reg] *= ac;
          yacc[1][reg] *= ac;
        }
      }
#pragma unroll
      for (int kt = 0; kt < 4; ++kt) {
        const int kt32 = kt >> 1, off = 4 * (kt & 1);
        unsigned int a0 = u[kt32][off + 0], a2 = u[kt32][off + 2];
        unsigned int a1 = u[kt32][off + 1], a3 = u[kt32][off + 3];
        asm("v_permlane32_swap_b32 %0, %1" : "+v"(a0), "+v"(a2));
        asm("v_permlane32_swap_b32 %0, %1" : "+v"(a1), "+v"(a3));
        uint4v pav = {a0, a1, a2, a3};
        bf16x8 paf = __builtin_bit_cast(bf16x8, pav);
#pragma unroll
        for (int dt = 0; dt < 2; ++dt) {
          bf16x8 vf = *(const bf16x8*)&Vs[cb][dt * 32 + lq][kt * 16 + hi * 8];
          yacc[dt] = __builtin_amdgcn_mfma_f32_32x32x16_bf16(paf, vf, yacc[dt], 0, 0, 0);
        }
      }
    }
  }
#pragma unroll
  for (int reg = 0; reg < 16; ++reg) {
    int row = (reg & 3) + 8 * (reg >> 2) + 4 * hi;
    float linv = 1.f / __shfl(l_r, row);
    int qg = q0w + row;
#pragma unroll
    for (int dt = 0; dt < 2; ++dt) {
      float v = yacc[dt][reg] * linv;
      ((unsigned short*)yb)[(size_t)(b * 2048 + qg) * 1024 + h * 64 + dt * 32 + lq] = f2bf(v);
    }
  }
}

extern "C" void kernel_launch(void* const* d_in, const int* in_sizes, int n_in,
                              void* d_out, int out_size, void* d_ws, size_t ws_size,
                              hipStream_t stream) {
  const float* x = (const float*)d_in[0];
  const float* W_attn = (const float*)d_in[1];
  const float* b_attn = (const float*)d_in[2];
  const float* W_proj = (const float*)d_in[3];
  const float* b_proj = (const float*)d_in[4];
  float* out = (float*)d_out;
  char* ws = (char*)d_ws;

  size_t off = 0;
  __bf16* WtA = (__bf16*)(ws + off); off += (size_t)3072 * 1024 * 2;
  __bf16* WtP = (__bf16*)(ws + off); off += (size_t)1024 * 1024 * 2;
  __bf16* qkv = (__bf16*)(ws + off); off += (size_t)8192 * 3072 * 2;
  __bf16* Qb  = (__bf16*)(ws + off); off += (size_t)64 * 2048 * 64 * 2;
  __bf16* Kb  = (__bf16*)(ws + off); off += (size_t)64 * 2048 * 64 * 2;
  __bf16* Vtb = (__bf16*)(ws + off); off += (size_t)64 * 2048 * 64 * 2;
  // xb (x in bf16) is dead after GEMM1; yb is only written after attn -> alias them
  __bf16* xyb = (__bf16*)(ws + off); off += (size_t)8192 * 1024 * 2;
  __bf16* xb = xyb;
  __bf16* yb = xyb;
  (void)ws_size; (void)in_sizes; (void)n_in; (void)out_size;

  f32_to_bf16_kernel<<<4096, 256, 0, stream>>>(x, xb);
  wtrans_kernel<<<dim3(3072 / 32, 1024 / 32), dim3(32, 8), 0, stream>>>(W_attn, WtA, 1024, 3072);
  wtrans_kernel<<<dim3(1024 / 32, 1024 / 32), dim3(32, 8), 0, stream>>>(W_proj, WtP, 1024, 1024);
  gemm_bt_kernel<0><<<dim3(24, 64), 256, 0, stream>>>(xb, WtA, b_attn, qkv, 8192, 3072, 1024);
  reshape_qk_kernel<<<4096, 256, 0, stream>>>(qkv, Qb, Kb);
  vtrans_kernel<<<dim3(32, 64), 256, 0, stream>>>(qkv, Vtb);
  attn_kernel<<<dim3(1024), 256, 0, stream>>>(Qb, Kb, Vtb, yb);
  gemm_bt_kernel<1><<<dim3(8, 64), 256, 0, stream>>>(yb, WtP, b_proj, out, 8192, 1024, 1024);
}

// Round 4
// 206.606 us; speedup vs baseline: 1.7248x; 1.0120x over previous
//
#include <hip/hip_runtime.h>

typedef __bf16 bf16x8 __attribute__((ext_vector_type(8)));
typedef float f32x4 __attribute__((ext_vector_type(4)));
typedef float f32x16 __attribute__((ext_vector_type(16)));
typedef unsigned short ushort8 __attribute__((ext_vector_type(8)));
typedef unsigned int uint4v __attribute__((ext_vector_type(4)));

__device__ __forceinline__ unsigned short f2bf(float f) {
  __bf16 b = (__bf16)f;
  return __builtin_bit_cast(unsigned short, b);
}
__device__ __forceinline__ float bf2f(unsigned short u) {
  unsigned int x = ((unsigned int)u) << 16;
  return __builtin_bit_cast(float, x);
}

// async global->LDS, 16B per lane; LDS dest must be wave-uniform base + lane*16
#define GLOAD_LDS16(g, l)                                              \
  __builtin_amdgcn_global_load_lds(                                    \
      (const __attribute__((address_space(1))) void*)(g),              \
      (__attribute__((address_space(3))) void*)(l), 16, 0, 0)

// ---------------- x f32 -> bf16 ----------------
__global__ __launch_bounds__(256) void f32_to_bf16_kernel(const float* __restrict__ in,
                                                          __bf16* __restrict__ out) {
  int i = blockIdx.x * 256 + threadIdx.x;
  const float4* p = (const float4*)(in + (size_t)i * 8);
  float4 f0 = p[0], f1 = p[1];
  ushort8 u = {f2bf(f0.x), f2bf(f0.y), f2bf(f0.z), f2bf(f0.w),
               f2bf(f1.x), f2bf(f1.y), f2bf(f1.z), f2bf(f1.w)};
  *(ushort8*)((unsigned short*)out + (size_t)i * 8) = u;
}

// ---------------- W transpose + f32->bf16 convert: Wt[n][k] = W[k][n] ----------------
__global__ __launch_bounds__(256) void wtrans_kernel(const float* __restrict__ W,
                                                     __bf16* __restrict__ Wt,
                                                     int K, int N) {
  __shared__ float tile[32][33];
  int tx = threadIdx.x, ty = threadIdx.y;  // block (32,8)
  int n0 = blockIdx.x * 32, k0 = blockIdx.y * 32;
#pragma unroll
  for (int i = 0; i < 32; i += 8)
    tile[ty + i][tx] = W[(size_t)(k0 + ty + i) * N + n0 + tx];
  __syncthreads();
#pragma unroll
  for (int i = 0; i < 32; i += 8)
    Wt[(size_t)(n0 + ty + i) * K + k0 + tx] = (__bf16)tile[tx][ty + i];
}

// ---------------- GEMM: C[M,N] = A[M,K] @ Bt[N,K]^T + bias (m97 structure) ----------------
template <int OUT_F32>
__global__ __launch_bounds__(256) void gemm_bt_kernel(const __bf16* __restrict__ Ab,
                                                      const __bf16* __restrict__ Bt,
                                                      const float* __restrict__ bias,
                                                      void* __restrict__ Cp,
                                                      int M, int N, int K) {
  __shared__ __align__(16) unsigned short As[128 * 32];
  __shared__ __align__(16) unsigned short Bs[128 * 32];
  const int tid = threadIdx.x;
  const int lane = tid & 63;
  const int wid = tid >> 6;
  const int lr = lane & 15, lg = lane >> 4;
  const int gx = gridDim.x;
  int nwg = gx * gridDim.y;
  int bid = blockIdx.y * gx + blockIdx.x;
  if ((nwg & 7) == 0) {
    int cpx = nwg >> 3;
    bid = (bid & 7) * cpx + (bid >> 3);
  }
  const int m0 = (bid / gx) * 128, n0 = (bid % gx) * 128;
  const int wm = (wid >> 1) * 64, wn = (wid & 1) * 64;
  const int sr = tid >> 2, sc = (tid & 3) * 8;
  const unsigned short* Ag = (const unsigned short*)Ab + (size_t)(m0 + sr) * K + sc;
  const unsigned short* Bg = (const unsigned short*)Bt + (size_t)(n0 + sr) * K + sc;
  f32x4 acc[4][4] = {};
  for (int k0 = 0; k0 < K; k0 += 32) {
    GLOAD_LDS16(Ag + k0, As + tid * 8);
    GLOAD_LDS16(Ag + (size_t)64 * K + k0, As + 2048 + tid * 8);
    GLOAD_LDS16(Bg + k0, Bs + tid * 8);
    GLOAD_LDS16(Bg + (size_t)64 * K + k0, Bs + 2048 + tid * 8);
    __syncthreads();
    bf16x8 af[4], bfr[4];
#pragma unroll
    for (int i = 0; i < 4; ++i) af[i] = *(const bf16x8*)&As[(wm + i * 16 + lr) * 32 + lg * 8];
#pragma unroll
    for (int i = 0; i < 4; ++i) bfr[i] = *(const bf16x8*)&Bs[(wn + i * 16 + lr) * 32 + lg * 8];
#pragma unroll
    for (int i = 0; i < 4; ++i)
#pragma unroll
      for (int jn = 0; jn < 4; ++jn)
        acc[i][jn] = __builtin_amdgcn_mfma_f32_16x16x32_bf16(af[i], bfr[jn], acc[i][jn], 0, 0, 0);
    __syncthreads();
  }
#pragma unroll
  for (int i = 0; i < 4; ++i)
#pragma unroll
    for (int jn = 0; jn < 4; ++jn)
#pragma unroll
      for (int jj = 0; jj < 4; ++jj) {
        int row = m0 + wm + i * 16 + lg * 4 + jj;
        int col = n0 + wn + jn * 16 + lr;
        float v = acc[i][jn][jj] + bias[col];
        if (OUT_F32)
          ((float*)Cp)[(size_t)row * N + col] = v;
        else
          ((unsigned short*)Cp)[(size_t)row * N + col] = f2bf(v);
      }
}

// ---------------- qkv(v part) -> Vt [B,H,D,T] (tiled transpose) ----------------
__global__ __launch_bounds__(256) void vtrans_kernel(const __bf16* __restrict__ qkv,
                                                     __bf16* __restrict__ Vt) {
  __shared__ __align__(16) unsigned short tile[64][72];
  int bh = blockIdx.y, b = bh >> 4, h = bh & 15;
  int t0 = blockIdx.x * 64;
  int tid = threadIdx.x;
#pragma unroll
  for (int p = 0; p < 2; ++p) {
    int idx = p * 256 + tid;
    int r = idx >> 3, c8 = (idx & 7) * 8;
    *(ushort8*)&tile[r][c8] = *(const ushort8*)((const unsigned short*)qkv +
                                                (size_t)(b * 2048 + t0 + r) * 3072 + 2048 +
                                                h * 64 + c8);
  }
  __syncthreads();
#pragma unroll
  for (int p = 0; p < 2; ++p) {
    int idx = p * 256 + tid;
    int d = idx >> 3, c8 = (idx & 7) * 8;
    ushort8 u;
#pragma unroll
    for (int i = 0; i < 8; ++i) u[i] = tile[c8 + i][d];
    *(ushort8*)((unsigned short*)Vt + (size_t)(bh * 64 + d) * 2048 + t0 + c8) = u;
  }
}

// ---------------- flash attention (causal), swapped-QK^T 32x32, T14 async-stage ----------------
// Q,K read directly from qkv; V from Vt. Q pre-scaled by 1/sqrt(d)*log2(e).
__global__ __launch_bounds__(256) void attn_kernel(const __bf16* __restrict__ qkvp,
                                                   const __bf16* __restrict__ Vt,
                                                   __bf16* __restrict__ yb) {
  __shared__ __align__(16) unsigned short Ks[2][64][72];
  __shared__ __align__(16) unsigned short Vs[2][64][72];
  const int bx = blockIdx.x;
  const int qb = 15 - (bx >> 6);  // heavy blocks first
  const int bh = bx & 63;
  const int b = bh >> 4, h = bh & 15;
  const int tid = threadIdx.x, wid = tid >> 6, lane = tid & 63;
  const int lq = lane & 31, hi = lane >> 5;
  const unsigned short* qkv = (const unsigned short*)qkvp;
  const unsigned short* Vh = (const unsigned short*)Vt + (size_t)bh * 64 * 2048;
  const int q0w = qb * 128 + wid * 32;
  const int jmax_w = 2 * qb + (wid >> 1);
  const int qrel = (wid & 1) * 32 + lq;
  const int J = 2 * qb + 2;
  // staging coords: thread covers rows r0,r1 (of 64), 8 cols each
  const int r0 = tid >> 3, r1 = 32 + (tid >> 3), c8 = (tid & 7) * 8;
  const unsigned short* Kcol = qkv + (size_t)b * 2048 * 3072 + 1024 + h * 64 + c8;

  // Q B-fragments, pre-scaled: lane holds sc*Q[q0w+lq][dc*16 + hi*8 + i]
  const float qs = 0.125f * 1.44269504f;
  bf16x8 qf[4];
  {
    const unsigned short* Qg = qkv + (size_t)(b * 2048 + q0w + lq) * 3072 + h * 64;
#pragma unroll
    for (int dc = 0; dc < 4; ++dc) {
      ushort8 uq = *(const ushort8*)(Qg + dc * 16 + hi * 8);
      uint4v w;
#pragma unroll
      for (int i = 0; i < 4; ++i) {
        float lo = bf2f(uq[2 * i]) * qs;
        float hh = bf2f(uq[2 * i + 1]) * qs;
        unsigned int up;
        asm("v_cvt_pk_bf16_f32 %0, %1, %2" : "=v"(up) : "v"(lo), "v"(hh));
        w[i] = up;
      }
      qf[dc] = __builtin_bit_cast(bf16x8, w);
    }
  }

  f32x16 yacc[2] = {};
  float m_r = -1e30f, l_r = 0.f;

  ushort8 kr0, kr1, vr0, vr1;
  auto issue_loads = [&](int jt) {
    kr0 = *(const ushort8*)(Kcol + (size_t)(jt * 64 + r0) * 3072);
    kr1 = *(const ushort8*)(Kcol + (size_t)(jt * 64 + r1) * 3072);
    vr0 = *(const ushort8*)(Vh + (size_t)r0 * 2048 + jt * 64 + c8);
    vr1 = *(const ushort8*)(Vh + (size_t)r1 * 2048 + jt * 64 + c8);
  };
  auto write_tile = [&](int bi) {
    *(ushort8*)&Ks[bi][r0][c8] = kr0;
    *(ushort8*)&Ks[bi][r1][c8] = kr1;
    *(ushort8*)&Vs[bi][r0][c8] = vr0;
    *(ushort8*)&Vs[bi][r1][c8] = vr1;
  };

  // prologue: tile 0 -> buf 0; issue loads for tile 1
  issue_loads(0);
  write_tile(0);
  if (J > 1) issue_loads(1);

  for (int j = 0; j < J; ++j) {
    __syncthreads();  // buf (j&1) holds tile j
    const int cb = j & 1;
    if (j <= jmax_w) {
      // --- S^T = K @ Q^T (Q pre-scaled)
      f32x16 sa[2];
      __builtin_amdgcn_s_setprio(1);
#pragma unroll
      for (int kt32 = 0; kt32 < 2; ++kt32) {
        f32x16 s = {};
#pragma unroll
        for (int dc = 0; dc < 4; ++dc) {
          bf16x8 kf = *(const bf16x8*)&Ks[cb][kt32 * 32 + lq][dc * 16 + hi * 8];
          s = __builtin_amdgcn_mfma_f32_32x32x16_bf16(kf, qf[dc], s, 0, 0, 0);
        }
        sa[kt32] = s;
      }
      __builtin_amdgcn_s_setprio(0);
      // --- causal mask (diagonal tile only, wave-uniform branch)
      if (j == jmax_w) {
#pragma unroll
        for (int kt32 = 0; kt32 < 2; ++kt32)
#pragma unroll
          for (int reg = 0; reg < 16; ++reg) {
            int kl = kt32 * 32 + (reg & 3) + 8 * (reg >> 2) + 4 * hi;
            if (kl > qrel) sa[kt32][reg] = -1e30f;
          }
      }
      // --- row max (pair-tree), defer-max
      float pmax = -1e30f;
#pragma unroll
      for (int kt32 = 0; kt32 < 2; ++kt32)
#pragma unroll
        for (int reg = 0; reg < 16; reg += 4)
          pmax = fmaxf(pmax, fmaxf(fmaxf(sa[kt32][reg], sa[kt32][reg + 1]),
                                   fmaxf(sa[kt32][reg + 2], sa[kt32][reg + 3])));
      pmax = fmaxf(pmax, __shfl_xor(pmax, 32));
      const bool need = __any(pmax > m_r + 8.f) != 0;
      const float mnew = need ? fmaxf(m_r, pmax) : m_r;
      const float alpha = exp2f(m_r - mnew);
      // --- exp + row sum + pack to bf16 pairs
      unsigned int u[2][8];
      float rs = 0.f;
#pragma unroll
      for (int kt32 = 0; kt32 < 2; ++kt32)
#pragma unroll
        for (int r = 0; r < 8; ++r) {
          float p0 = exp2f(sa[kt32][2 * r] - mnew);
          float p1 = exp2f(sa[kt32][2 * r + 1] - mnew);
          rs += p0 + p1;
          unsigned int up;
          asm("v_cvt_pk_bf16_f32 %0, %1, %2" : "=v"(up) : "v"(p0), "v"(p1));
          u[kt32][r] = up;
        }
      rs += __shfl_xor(rs, 32);
      l_r = l_r * alpha + rs;
      m_r = mnew;
      if (need) {
#pragma unroll
        for (int reg = 0; reg < 16; ++reg) {
          int row = (reg & 3) + 8 * (reg >> 2) + 4 * hi;
          float ac = __shfl(alpha, row);
          yacc[0][reg] *= ac;
          yacc[1][reg] *= ac;
        }
      }
      // --- PV: repack P via permlane32_swap, accumulate Y
      __builtin_amdgcn_s_setprio(1);
#pragma unroll
      for (int kt = 0; kt < 4; ++kt) {
        const int kt32 = kt >> 1, off = 4 * (kt & 1);
        unsigned int a0 = u[kt32][off + 0], a2 = u[kt32][off + 2];
        unsigned int a1 = u[kt32][off + 1], a3 = u[kt32][off + 3];
        asm("v_permlane32_swap_b32 %0, %1" : "+v"(a0), "+v"(a2));
        asm("v_permlane32_swap_b32 %0, %1" : "+v"(a1), "+v"(a3));
        uint4v pav = {a0, a1, a2, a3};
        bf16x8 paf = __builtin_bit_cast(bf16x8, pav);
#pragma unroll
        for (int dt = 0; dt < 2; ++dt) {
          bf16x8 vf = *(const bf16x8*)&Vs[cb][dt * 32 + lq][kt * 16 + hi * 8];
          yacc[dt] = __builtin_amdgcn_mfma_f32_32x32x16_bf16(paf, vf, yacc[dt], 0, 0, 0);
        }
      }
      __builtin_amdgcn_s_setprio(0);
    }
    // --- T14 write-late: stage tile j+1 into the other buffer after compute
    if (j + 1 < J) {
      write_tile(cb ^ 1);
      if (j + 2 < J) issue_loads(j + 2);
    }
  }
  // --- epilogue
#pragma unroll
  for (int reg = 0; reg < 16; ++reg) {
    int row = (reg & 3) + 8 * (reg >> 2) + 4 * hi;
    float linv = 1.f / __shfl(l_r, row);
    int qg = q0w + row;
#pragma unroll
    for (int dt = 0; dt < 2; ++dt) {
      float v = yacc[dt][reg] * linv;
      ((unsigned short*)yb)[(size_t)(b * 2048 + qg) * 1024 + h * 64 + dt * 32 + lq] = f2bf(v);
    }
  }
}

extern "C" void kernel_launch(void* const* d_in, const int* in_sizes, int n_in,
                              void* d_out, int out_size, void* d_ws, size_t ws_size,
                              hipStream_t stream) {
  const float* x = (const float*)d_in[0];
  const float* W_attn = (const float*)d_in[1];
  const float* b_attn = (const float*)d_in[2];
  const float* W_proj = (const float*)d_in[3];
  const float* b_proj = (const float*)d_in[4];
  float* out = (float*)d_out;
  char* ws = (char*)d_ws;

  size_t off = 0;
  __bf16* WtA = (__bf16*)(ws + off); off += (size_t)3072 * 1024 * 2;
  __bf16* WtP = (__bf16*)(ws + off); off += (size_t)1024 * 1024 * 2;
  __bf16* qkv = (__bf16*)(ws + off); off += (size_t)8192 * 3072 * 2;
  __bf16* Vtb = (__bf16*)(ws + off); off += (size_t)64 * 2048 * 64 * 2;
  // xb (x in bf16) is dead after GEMM1; yb written only after attn -> alias
  __bf16* xyb = (__bf16*)(ws + off); off += (size_t)8192 * 1024 * 2;
  __bf16* xb = xyb;
  __bf16* yb = xyb;
  (void)ws_size; (void)in_sizes; (void)n_in; (void)out_size;

  f32_to_bf16_kernel<<<4096, 256, 0, stream>>>(x, xb);
  wtrans_kernel<<<dim3(3072 / 32, 1024 / 32), dim3(32, 8), 0, stream>>>(W_attn, WtA, 1024, 3072);
  wtrans_kernel<<<dim3(1024 / 32, 1024 / 32), dim3(32, 8), 0, stream>>>(W_proj, WtP, 1024, 1024);
  gemm_bt_kernel<0><<<dim3(24, 64), 256, 0, stream>>>(xb, WtA, b_attn, qkv, 8192, 3072, 1024);
  vtrans_kernel<<<dim3(32, 64), 256, 0, stream>>>(qkv, Vtb);
  attn_kernel<<<dim3(1024), 256, 0, stream>>>(qkv, Vtb, yb);
  gemm_bt_kernel<1><<<dim3(8, 64), 256, 0, stream>>>(yb, WtP, b_proj, out, 8192, 1024, 1024);
}